// Round 3
// baseline (1083.160 us; speedup 1.0000x reference)
//
#include <hip/hip_runtime.h>
#include <cstdint>
#include <cstddef>

#define S_NUM 100000
#define T_NUM 20000
#define E_NUM 1000000

#define NB   625      // buckets (T / GT)
#define GT   32       // targets per bucket
#define CAP  2560     // entries per bucket slot (mean 1600, sd ~40)
#define CH   4096     // edges per partition chunk

typedef __bf16 bf16x8 __attribute__((ext_vector_type(8)));
typedef float f32x4 __attribute__((ext_vector_type(4)));

__device__ __forceinline__ unsigned short f2bf(float f) {
  unsigned int u = __float_as_uint(f);
  u += 0x7fffu + ((u >> 16) & 1u);   // round-to-nearest-even
  return (unsigned short)(u >> 16);
}
__device__ __forceinline__ float bflo(unsigned int v) { return __uint_as_float(v << 16); }
__device__ __forceinline__ float bfhi(unsigned int v) { return __uint_as_float(v & 0xffff0000u); }

// K0: embed [256,128] f32 -> embT [128 n][256 k] bf16 (transposed for B-operand staging)
__global__ void k0_prep(const float* __restrict__ embed, unsigned short* __restrict__ embT) {
  int idx = blockIdx.x * blockDim.x + threadIdx.x;  // 0..32767
  int n = idx & 127, k = idx >> 7;
  embT[n * 256 + k] = f2bf(embed[k * 128 + n]);
}

// K1: xb[S,128] bf16 = bf16( (sf[0:S,0:256] @ embed) / xn ).
__launch_bounds__(256)
__global__ void k1_gemm(const float* __restrict__ sf, const float* __restrict__ xn,
                        const unsigned short* __restrict__ embT,
                        unsigned short* __restrict__ xb) {
  __shared__ unsigned short lA[128][40];
  __shared__ unsigned short lB[128][40];
  const int tid = threadIdx.x;
  const int wave = tid >> 6;
  const int lane = tid & 63;
  const int quad = lane >> 4;
  const int l15 = lane & 15;
  const int row0 = blockIdx.x * 128;

  f32x4 acc[8][2];
#pragma unroll
  for (int i = 0; i < 8; ++i)
#pragma unroll
    for (int j = 0; j < 2; ++j) acc[i][j] = (f32x4){0.f, 0.f, 0.f, 0.f};

  const int ar = tid >> 1;
  const int aseg = (tid & 1) * 16;

  for (int kc = 0; kc < 8; ++kc) {
    const int k0 = kc * 32;
    {  // stage A chunk [128 x 32] f32 -> bf16
      const int gr = row0 + ar;
      float4 v[4];
      if (gr < S_NUM) {
        const float4* p = (const float4*)(sf + (size_t)gr * 256 + k0 + aseg);
        v[0] = p[0]; v[1] = p[1]; v[2] = p[2]; v[3] = p[3];
      } else {
        v[0] = v[1] = v[2] = v[3] = make_float4(0.f, 0.f, 0.f, 0.f);
      }
      unsigned short* dst = &lA[ar][aseg];
#pragma unroll
      for (int i = 0; i < 4; ++i) {
        dst[i * 4 + 0] = f2bf(v[i].x); dst[i * 4 + 1] = f2bf(v[i].y);
        dst[i * 4 + 2] = f2bf(v[i].z); dst[i * 4 + 3] = f2bf(v[i].w);
      }
    }
    {  // stage B^T chunk [128 n x 32 k] bf16
      const ushort4* p = (const ushort4*)(embT + ar * 256 + k0 + aseg);
      ushort4* d2 = (ushort4*)&lB[ar][aseg];
      d2[0] = p[0]; d2[1] = p[1]; d2[2] = p[2]; d2[3] = p[3];
    }
    __syncthreads();
    bf16x8 fb[2];
#pragma unroll
    for (int ct = 0; ct < 2; ++ct)
      fb[ct] = *(const bf16x8*)&lB[wave * 32 + ct * 16 + l15][quad * 8];
#pragma unroll
    for (int rt = 0; rt < 8; ++rt) {
      bf16x8 fa = *(const bf16x8*)&lA[rt * 16 + l15][quad * 8];
      acc[rt][0] = __builtin_amdgcn_mfma_f32_16x16x32_bf16(fa, fb[0], acc[rt][0], 0, 0, 0);
      acc[rt][1] = __builtin_amdgcn_mfma_f32_16x16x32_bf16(fa, fb[1], acc[rt][1], 0, 0, 0);
    }
    __syncthreads();
  }
  const int col0 = wave * 32;
#pragma unroll
  for (int rt = 0; rt < 8; ++rt) {
#pragma unroll
    for (int reg = 0; reg < 4; ++reg) {
      const int r = row0 + rt * 16 + quad * 4 + reg;
      if (r < S_NUM) {
        const float inv = __builtin_amdgcn_rcpf(xn[r]);
        xb[(size_t)r * 128 + col0 + l15]      = f2bf(acc[rt][0][reg] * inv);
        xb[(size_t)r * 128 + col0 + 16 + l15] = f2bf(acc[rt][1][reg] * inv);
      }
    }
  }
}

// K2: partition edges into NB buckets of GT targets each.
// Per chunk: LDS histogram -> one global atomic reserve per bucket -> direct
// scatter at base+rank (consecutive per bucket => L2 write-combines lines).
// Entry = (dst & 31) << 17 | src   (src < 2^17).
__launch_bounds__(256)
__global__ void k2_partition(const int* __restrict__ src_idx, const int* __restrict__ dst_idx,
                             int* __restrict__ gcursor, unsigned int* __restrict__ ebuf) {
  __shared__ int bcnt[NB];
  __shared__ int gbase[NB];
  const int tid = threadIdx.x;
  for (int c = blockIdx.x; c * CH < E_NUM; c += gridDim.x) {
    const int e0 = c * CH;
    const int e1 = (e0 + CH < E_NUM) ? (e0 + CH) : E_NUM;
    for (int i = tid; i < NB; i += 256) bcnt[i] = 0;
    __syncthreads();
    for (int e = e0 + tid; e < e1; e += 256)
      atomicAdd(&bcnt[dst_idx[e] >> 5], 1);
    __syncthreads();
    for (int i = tid; i < NB; i += 256) {
      const int cnt = bcnt[i];
      gbase[i] = (cnt > 0) ? atomicAdd(&gcursor[i], cnt) : 0;
      bcnt[i] = 0;  // reuse as rank counter
    }
    __syncthreads();
    for (int e = e0 + tid; e < e1; e += 256) {
      const int d = dst_idx[e];
      const int s = src_idx[e];
      const int b = d >> 5;
      const int r = atomicAdd(&bcnt[b], 1);
      const int pos = gbase[b] + r;
      if (pos < CAP)
        ebuf[(size_t)b * CAP + pos] = ((unsigned int)(d & 31) << 17) | (unsigned int)s;
    }
    __syncthreads();
  }
}

// K3: per-bucket aggregation. Block = 256 thr (4 waves) handles GT=32 targets.
// LDS fp32 accumulators + counts; 4-deep gather ILP; writes aggr as bf16.
__launch_bounds__(256)
__global__ void k3_aggr(const int* __restrict__ gcursor, const unsigned int* __restrict__ ebuf,
                        const unsigned short* __restrict__ xb, unsigned short* __restrict__ aggr) {
  __shared__ float accum[GT][128];
  __shared__ int cnt[GT];
  const int b = blockIdx.x;
  const int tid = threadIdx.x;
  const int wave = tid >> 6, lane = tid & 63;
  for (int i = tid; i < GT * 128; i += 256) (&accum[0][0])[i] = 0.f;
  if (tid < GT) cnt[tid] = 0;
  __syncthreads();

  int n = gcursor[b];
  if (n > CAP) n = CAP;
  const unsigned int* eb = ebuf + (size_t)b * CAP;

  for (int base = wave * 4; base < n; base += 16) {
    const int m = (n - base < 4) ? (n - base) : 4;
    const uint4 ew = *(const uint4*)(eb + base);  // uniform -> scalar load
    unsigned int e[4] = {ew.x, ew.y, ew.z, ew.w};
    unsigned int v[4];
    int dl[4];
#pragma unroll
    for (int j = 0; j < 4; ++j) {
      if (j < m) {
        const int s = (int)(e[j] & 0x1FFFFu);
        dl[j] = (int)(e[j] >> 17);
        v[j] = *(const unsigned int*)(xb + (size_t)s * 128 + 2 * lane);
      }
    }
#pragma unroll
    for (int j = 0; j < 4; ++j) {
      if (j < m) {
        atomicAdd(&accum[dl[j]][2 * lane], bflo(v[j]));
        atomicAdd(&accum[dl[j]][2 * lane + 1], bfhi(v[j]));
        if (lane == 0) atomicAdd(&cnt[dl[j]], 1);
      }
    }
  }
  __syncthreads();
  // divide by count, store bf16 (packed u32 pairs)
  for (int i = tid; i < GT * 64; i += 256) {
    const int d = i >> 6;
    const int kw = i & 63;
    const int c = cnt[d];
    const float inv = (c > 0) ? __builtin_amdgcn_rcpf((float)c) : 0.f;
    const unsigned short h0 = f2bf(accum[d][2 * kw] * inv);
    const unsigned short h1 = f2bf(accum[d][2 * kw + 1] * inv);
    *(unsigned int*)(aggr + ((size_t)b * GT + d) * 128 + 2 * kw) =
        (unsigned int)h0 | ((unsigned int)h1 << 16);
  }
}

// K6: out[T,128] = aggr[T,128](bf16) @ weight[128,128], fp32 LDS tiles
__global__ void k6_out(const unsigned short* __restrict__ aggr, const float* __restrict__ W,
                       float* __restrict__ out) {
  __shared__ float lA[16][128];
  __shared__ float lW[128][16];
  const int tid = threadIdx.x;
  const int tx = tid & 15, ty = tid >> 4;
  const int r0 = blockIdx.x * 16, c0 = blockIdx.y * 16;
#pragma unroll
  for (int i = 0; i < 4; ++i) {  // A: 16x128 bf16 = 1024 u32 words
    const int idx = i * 256 + tid;
    const int row = idx >> 6, wc = idx & 63;
    const unsigned int v = *(const unsigned int*)(aggr + (size_t)(r0 + row) * 128 + wc * 2);
    lA[row][wc * 2] = bflo(v);
    lA[row][wc * 2 + 1] = bfhi(v);
  }
#pragma unroll
  for (int i = 0; i < 8; ++i) {
    const int idx = i * 256 + tid;
    const int k = idx >> 4, c = idx & 15;
    lW[k][c] = W[(size_t)k * 128 + c0 + c];
  }
  __syncthreads();
  float acc = 0.f;
#pragma unroll
  for (int k = 0; k < 128; ++k) acc += lA[ty][k] * lW[k][tx];
  out[(size_t)(r0 + ty) * 128 + c0 + tx] = acc;
}

extern "C" void kernel_launch(void* const* d_in, const int* in_sizes, int n_in,
                              void* d_out, int out_size, void* d_ws, size_t ws_size,
                              hipStream_t stream) {
  const float* sf      = (const float*)d_in[0];   // [N,256] f32 (only rows < S used)
  const int*   src_idx = (const int*)d_in[1];     // [E]
  const int*   dst_idx = (const int*)d_in[2];     // [E]
  /* d_in[3] range_list: unused */
  const float* xn      = (const float*)d_in[4];   // [N]
  const float* embed   = (const float*)d_in[5];   // [256,128]
  const float* weight  = (const float*)d_in[6];   // [128,128]
  float* out = (float*)d_out;                     // [T,128] f32

  // workspace layout (16B-aligned), total ~37.2 MB
  char* w = (char*)d_ws;
  unsigned short* xb   = (unsigned short*)(w);               // 25,600,000
  unsigned short* embT = (unsigned short*)(w + 25600000);    // 65,536
  int* gcursor = (int*)(w + 25665536);                       // 4,096 (625 used)
  unsigned int* ebuf = (unsigned int*)(w + 25669632);        // 625*2560*4 + 64 slack
  unsigned short* aggr = (unsigned short*)(w + 32069696);    // 20000*128*2 = 5,120,000

  hipMemsetAsync(gcursor, 0, 4096, stream);
  k0_prep<<<128, 256, 0, stream>>>(embed, embT);
  k1_gemm<<<(S_NUM + 127) / 128, 256, 0, stream>>>(sf, xn, embT, xb);
  k2_partition<<<(E_NUM + CH - 1) / CH, 256, 0, stream>>>(src_idx, dst_idx, gcursor, ebuf);
  k3_aggr<<<NB, 256, 0, stream>>>(gcursor, ebuf, xb, aggr);
  k6_out<<<dim3(T_NUM / 16, 8), 256, 0, stream>>>(aggr, weight, out);
}

// Round 4
// 362.101 us; speedup vs baseline: 2.9913x; 2.9913x over previous
//
#include <hip/hip_runtime.h>
#include <cstdint>
#include <cstddef>

#define S_NUM 100000
#define T_NUM 20000
#define E_NUM 1000000

#define NB   625      // buckets (T / GT)
#define GT   32       // targets per bucket
#define CAP  2560     // entries per bucket slot (mean 1600, sd ~40)
#define CH   4096     // edges per partition chunk

typedef __bf16 bf16x8 __attribute__((ext_vector_type(8)));
typedef float f32x4 __attribute__((ext_vector_type(4)));

__device__ __forceinline__ unsigned short f2bf(float f) {
  unsigned int u = __float_as_uint(f);
  u += 0x7fffu + ((u >> 16) & 1u);   // round-to-nearest-even
  return (unsigned short)(u >> 16);
}
__device__ __forceinline__ float bflo(unsigned int v) { return __uint_as_float(v << 16); }
__device__ __forceinline__ float bfhi(unsigned int v) { return __uint_as_float(v & 0xffff0000u); }

// K0: embed [256,128] f32 -> embT [128 n][256 k] bf16
__global__ void k0_prep(const float* __restrict__ embed, unsigned short* __restrict__ embT) {
  int idx = blockIdx.x * blockDim.x + threadIdx.x;  // 0..32767
  int n = idx & 127, k = idx >> 7;
  embT[n * 256 + k] = f2bf(embed[k * 128 + n]);
}

// K1: xb[S,128] bf16 = bf16( (sf[0:S,0:256] @ embed) / xn ).
// LDS-free: B fragments preloaded to registers (64 VGPR/wave), A fragments
// loaded from global directly in MFMA layout (rows -> l15, k -> quad*8+j;
// per wave: 16 segments of 128 contiguous bytes), converted f32->bf16 in regs.
__launch_bounds__(256)
__global__ void k1_gemm(const float* __restrict__ sf, const float* __restrict__ xn,
                        const unsigned short* __restrict__ embT,
                        unsigned short* __restrict__ xb) {
  const int tid = threadIdx.x;
  const int wave = tid >> 6;
  const int lane = tid & 63;
  const int quad = lane >> 4;
  const int l15 = lane & 15;
  const int row0 = blockIdx.x * 128;

  // Preload all B fragments for this wave's 32 output cols: fb[kc][ct]
  bf16x8 fb[8][2];
#pragma unroll
  for (int kc = 0; kc < 8; ++kc)
#pragma unroll
    for (int ct = 0; ct < 2; ++ct) {
      const int n = wave * 32 + ct * 16 + l15;
      fb[kc][ct] = *(const bf16x8*)(embT + (size_t)n * 256 + kc * 32 + quad * 8);
    }

  f32x4 acc[8][2];
#pragma unroll
  for (int i = 0; i < 8; ++i)
#pragma unroll
    for (int j = 0; j < 2; ++j) acc[i][j] = (f32x4){0.f, 0.f, 0.f, 0.f};

  for (int kc = 0; kc < 8; ++kc) {
    float4 av[8][2];
#pragma unroll
    for (int rt = 0; rt < 8; ++rt) {
      const int gr = row0 + rt * 16 + l15;
      if (gr < S_NUM) {
        const float4* p = (const float4*)(sf + (size_t)gr * 256 + kc * 32 + quad * 8);
        av[rt][0] = p[0];
        av[rt][1] = p[1];
      } else {
        av[rt][0] = make_float4(0.f, 0.f, 0.f, 0.f);
        av[rt][1] = make_float4(0.f, 0.f, 0.f, 0.f);
      }
    }
#pragma unroll
    for (int rt = 0; rt < 8; ++rt) {
      union { unsigned short h[8]; bf16x8 v; } fa;
      fa.h[0] = f2bf(av[rt][0].x); fa.h[1] = f2bf(av[rt][0].y);
      fa.h[2] = f2bf(av[rt][0].z); fa.h[3] = f2bf(av[rt][0].w);
      fa.h[4] = f2bf(av[rt][1].x); fa.h[5] = f2bf(av[rt][1].y);
      fa.h[6] = f2bf(av[rt][1].z); fa.h[7] = f2bf(av[rt][1].w);
      acc[rt][0] = __builtin_amdgcn_mfma_f32_16x16x32_bf16(fa.v, fb[kc][0], acc[rt][0], 0, 0, 0);
      acc[rt][1] = __builtin_amdgcn_mfma_f32_16x16x32_bf16(fa.v, fb[kc][1], acc[rt][1], 0, 0, 0);
    }
  }
  // epilogue: D col = lane&15, row = quad*4+reg
  const int col0 = wave * 32;
#pragma unroll
  for (int rt = 0; rt < 8; ++rt) {
#pragma unroll
    for (int reg = 0; reg < 4; ++reg) {
      const int r = row0 + rt * 16 + quad * 4 + reg;
      if (r < S_NUM) {
        const float inv = __builtin_amdgcn_rcpf(xn[r]);
        xb[(size_t)r * 128 + col0 + l15]      = f2bf(acc[rt][0][reg] * inv);
        xb[(size_t)r * 128 + col0 + 16 + l15] = f2bf(acc[rt][1][reg] * inv);
      }
    }
  }
}

// K2: partition edges into NB buckets of GT targets each.
// Entry = (dst & 31) << 17 | src.
__launch_bounds__(512)
__global__ void k2_partition(const int* __restrict__ src_idx, const int* __restrict__ dst_idx,
                             int* __restrict__ gcursor, unsigned int* __restrict__ ebuf) {
  __shared__ int bcnt[NB];
  __shared__ int gbase[NB];
  const int tid = threadIdx.x;
  for (int c = blockIdx.x; c * CH < E_NUM; c += gridDim.x) {
    const int e0 = c * CH;
    const int e1 = (e0 + CH < E_NUM) ? (e0 + CH) : E_NUM;
    for (int i = tid; i < NB; i += 512) bcnt[i] = 0;
    __syncthreads();
    for (int e = e0 + tid; e < e1; e += 512)
      atomicAdd(&bcnt[dst_idx[e] >> 5], 1);
    __syncthreads();
    for (int i = tid; i < NB; i += 512) {
      const int cnt = bcnt[i];
      gbase[i] = (cnt > 0) ? atomicAdd(&gcursor[i], cnt) : 0;
      bcnt[i] = 0;  // reuse as rank counter
    }
    __syncthreads();
    for (int e = e0 + tid; e < e1; e += 512) {
      const int d = dst_idx[e];
      const int s = src_idx[e];
      const int b = d >> 5;
      const int r = atomicAdd(&bcnt[b], 1);
      const int pos = gbase[b] + r;
      if (pos < CAP)
        ebuf[(size_t)b * CAP + pos] = ((unsigned int)(d & 31) << 17) | (unsigned int)s;
    }
    __syncthreads();
  }
}

// K3: within-bucket counting sort -> per-target CSR.
// One block per bucket: 32-counter histogram, serial scan, scatter into
// ssorted (contiguous 10 KB region), emit tstart/tcnt per target.
__launch_bounds__(256)
__global__ void k3_sort(const int* __restrict__ gcursor, const unsigned int* __restrict__ ebuf,
                        unsigned int* __restrict__ ssorted, int* __restrict__ tstart,
                        int* __restrict__ tcnt) {
  __shared__ int hist[GT];
  __shared__ int scan[GT];
  __shared__ int cur[GT];
  const int b = blockIdx.x;
  const int tid = threadIdx.x;
  int n = gcursor[b];
  if (n > CAP) n = CAP;
  const unsigned int* eb = ebuf + (size_t)b * CAP;

  if (tid < GT) hist[tid] = 0;
  __syncthreads();
  for (int i = tid; i < n; i += 256) atomicAdd(&hist[eb[i] >> 17], 1);
  __syncthreads();
  if (tid == 0) {
    int run = 0;
#pragma unroll
    for (int i = 0; i < GT; ++i) { scan[i] = run; run += hist[i]; }
  }
  __syncthreads();
  if (tid < GT) {
    tstart[b * GT + tid] = b * CAP + scan[tid];
    tcnt[b * GT + tid] = hist[tid];
    cur[tid] = scan[tid];
  }
  __syncthreads();
  for (int i = tid; i < n; i += 256) {
    const unsigned int e = eb[i];
    const int dl = (int)(e >> 17);
    const int r = atomicAdd(&cur[dl], 1);
    ssorted[(size_t)b * CAP + r] = e & 0x1FFFFu;
  }
}

// K4: one wave per target; 4-deep independent gathers, register accumulators.
__launch_bounds__(256)
__global__ void k4_aggr(const int* __restrict__ tstart, const int* __restrict__ tcnt,
                        const unsigned int* __restrict__ ssorted,
                        const unsigned short* __restrict__ xb,
                        unsigned short* __restrict__ aggr) {
  const int wave = threadIdx.x >> 6, lane = threadIdx.x & 63;
  const int t = blockIdx.x * 4 + wave;  // grid = T/4, exact
  const int beg = tstart[t];
  const int cnt = tcnt[t];
  float a0 = 0.f, a1 = 0.f, b0 = 0.f, b1 = 0.f;
  int e = 0;
  for (; e + 4 <= cnt; e += 4) {
    const int s0 = (int)ssorted[beg + e];
    const int s1 = (int)ssorted[beg + e + 1];
    const int s2 = (int)ssorted[beg + e + 2];
    const int s3 = (int)ssorted[beg + e + 3];
    const unsigned int v0 = *(const unsigned int*)(xb + (size_t)s0 * 128 + 2 * lane);
    const unsigned int v1 = *(const unsigned int*)(xb + (size_t)s1 * 128 + 2 * lane);
    const unsigned int v2 = *(const unsigned int*)(xb + (size_t)s2 * 128 + 2 * lane);
    const unsigned int v3 = *(const unsigned int*)(xb + (size_t)s3 * 128 + 2 * lane);
    a0 += bflo(v0); a1 += bfhi(v0);
    b0 += bflo(v1); b1 += bfhi(v1);
    a0 += bflo(v2); a1 += bfhi(v2);
    b0 += bflo(v3); b1 += bfhi(v3);
  }
  for (; e < cnt; ++e) {
    const int s0 = (int)ssorted[beg + e];
    const unsigned int v0 = *(const unsigned int*)(xb + (size_t)s0 * 128 + 2 * lane);
    a0 += bflo(v0); a1 += bfhi(v0);
  }
  a0 += b0; a1 += b1;
  const float inv = (cnt > 0) ? __builtin_amdgcn_rcpf((float)cnt) : 0.f;
  const unsigned short h0 = f2bf(a0 * inv);
  const unsigned short h1 = f2bf(a1 * inv);
  *(unsigned int*)(aggr + (size_t)t * 128 + 2 * lane) =
      (unsigned int)h0 | ((unsigned int)h1 << 16);
}

// K6: out[T,128] = aggr[T,128](bf16) @ weight[128,128], fp32 LDS tiles
__global__ void k6_out(const unsigned short* __restrict__ aggr, const float* __restrict__ W,
                       float* __restrict__ out) {
  __shared__ float lA[16][128];
  __shared__ float lW[128][16];
  const int tid = threadIdx.x;
  const int tx = tid & 15, ty = tid >> 4;
  const int r0 = blockIdx.x * 16, c0 = blockIdx.y * 16;
#pragma unroll
  for (int i = 0; i < 4; ++i) {  // A: 16x128 bf16 = 1024 u32 words
    const int idx = i * 256 + tid;
    const int row = idx >> 6, wc = idx & 63;
    const unsigned int v = *(const unsigned int*)(aggr + (size_t)(r0 + row) * 128 + wc * 2);
    lA[row][wc * 2] = bflo(v);
    lA[row][wc * 2 + 1] = bfhi(v);
  }
#pragma unroll
  for (int i = 0; i < 8; ++i) {
    const int idx = i * 256 + tid;
    const int k = idx >> 4, c = idx & 15;
    lW[k][c] = W[(size_t)k * 128 + c0 + c];
  }
  __syncthreads();
  float acc = 0.f;
#pragma unroll
  for (int k = 0; k < 128; ++k) acc += lA[ty][k] * lW[k][tx];
  out[(size_t)(r0 + ty) * 128 + c0 + tx] = acc;
}

extern "C" void kernel_launch(void* const* d_in, const int* in_sizes, int n_in,
                              void* d_out, int out_size, void* d_ws, size_t ws_size,
                              hipStream_t stream) {
  const float* sf      = (const float*)d_in[0];   // [N,256] f32 (only rows < S used)
  const int*   src_idx = (const int*)d_in[1];     // [E]
  const int*   dst_idx = (const int*)d_in[2];     // [E]
  /* d_in[3] range_list: unused */
  const float* xn      = (const float*)d_in[4];   // [N]
  const float* embed   = (const float*)d_in[5];   // [256,128]
  const float* weight  = (const float*)d_in[6];   // [128,128]
  float* out = (float*)d_out;                     // [T,128] f32

  // workspace layout (16B-aligned), total ~38.6 MB
  char* w = (char*)d_ws;
  unsigned short* xb    = (unsigned short*)(w);              // 25,600,000
  unsigned short* embT  = (unsigned short*)(w + 25600000);   // 65,536
  int* gcursor          = (int*)(w + 25665536);              // 4,096 (625 used)
  unsigned int* ebuf    = (unsigned int*)(w + 25669632);     // 625*2560*4 = 6,400,000
  unsigned int* ssorted = (unsigned int*)(w + 32069632);     // 6,400,000
  int* tstart           = (int*)(w + 38469632);              // 80,000
  int* tcnt             = (int*)(w + 38549632);              // 80,000
  // aggr aliases ebuf (ebuf is dead after k3_sort)
  unsigned short* aggr  = (unsigned short*)(w + 25669632);   // 20000*128*2 = 5,120,000

  hipMemsetAsync(gcursor, 0, 4096, stream);
  k0_prep<<<128, 256, 0, stream>>>(embed, embT);
  k1_gemm<<<(S_NUM + 127) / 128, 256, 0, stream>>>(sf, xn, embT, xb);
  k2_partition<<<(E_NUM + CH - 1) / CH, 512, 0, stream>>>(src_idx, dst_idx, gcursor, ebuf);
  k3_sort<<<NB, 256, 0, stream>>>(gcursor, ebuf, ssorted, tstart, tcnt);
  k4_aggr<<<T_NUM / 4, 256, 0, stream>>>(tstart, tcnt, ssorted, xb, aggr);
  k6_out<<<dim3(T_NUM / 16, 8), 256, 0, stream>>>(aggr, weight, out);
}

// Round 5
// 315.440 us; speedup vs baseline: 3.4338x; 1.1479x over previous
//
#include <hip/hip_runtime.h>
#include <cstdint>
#include <cstddef>

#define S_NUM 100000
#define T_NUM 20000
#define E_NUM 1000000

#define NB   625      // buckets (T / GT)
#define GT   32       // targets per bucket
#define CAP  2560     // entries per bucket slot (mean 1600, sd ~40)
#define CH   4096     // edges per partition chunk

typedef __bf16 bf16x8 __attribute__((ext_vector_type(8)));
typedef float f32x4 __attribute__((ext_vector_type(4)));

__device__ __forceinline__ unsigned short f2bf(float f) {
  unsigned int u = __float_as_uint(f);
  u += 0x7fffu + ((u >> 16) & 1u);   // round-to-nearest-even
  return (unsigned short)(u >> 16);
}
__device__ __forceinline__ unsigned int f2bf2(float lo, float hi) {
  return (unsigned int)f2bf(lo) | ((unsigned int)f2bf(hi) << 16);
}
__device__ __forceinline__ float bflo(unsigned int v) { return __uint_as_float(v << 16); }
__device__ __forceinline__ float bfhi(unsigned int v) { return __uint_as_float(v & 0xffff0000u); }

// K0: embed [256,128] f32 -> embT [128 n][256 k] bf16
__global__ void k0_prep(const float* __restrict__ embed, unsigned short* __restrict__ embT) {
  int idx = blockIdx.x * blockDim.x + threadIdx.x;  // 0..32767
  int n = idx & 127, k = idx >> 7;
  embT[n * 256 + k] = f2bf(embed[k * 128 + n]);
}

// K1: xb[S,128] bf16 = bf16( (sf[0:S,0:256] @ embed) / xn ).
// A staged through LDS (coalesced f32 loads, convert-once during staging,
// padded rows -> conflict-free ds_read_b128). B preloaded in registers.
// Epilogue transposes through LDS for fully-coalesced 16B stores.
__launch_bounds__(256)
__global__ void k1_gemm(const float* __restrict__ sf, const float* __restrict__ xn,
                        const unsigned short* __restrict__ embT,
                        unsigned short* __restrict__ xb) {
  // union: staging tile [128][40] shorts (80B rows) / epilogue tile [128][136]
  __shared__ __align__(16) unsigned char smem[128 * 136 * 2];
  unsigned short (*lA)[40]  = (unsigned short (*)[40])smem;
  unsigned short (*lC)[136] = (unsigned short (*)[136])smem;

  const int tid = threadIdx.x;
  const int wave = tid >> 6;
  const int lane = tid & 63;
  const int quad = lane >> 4;
  const int l15 = lane & 15;
  const int row0 = blockIdx.x * 128;

  // Preload all B fragments for this wave's 32 output cols: fb[kc][ct]
  bf16x8 fb[8][2];
#pragma unroll
  for (int kc = 0; kc < 8; ++kc)
#pragma unroll
    for (int ct = 0; ct < 2; ++ct) {
      const int n = wave * 32 + ct * 16 + l15;
      fb[kc][ct] = *(const bf16x8*)(embT + (size_t)n * 256 + kc * 32 + quad * 8);
    }

  f32x4 acc[8][2];
#pragma unroll
  for (int i = 0; i < 8; ++i)
#pragma unroll
    for (int j = 0; j < 2; ++j) acc[i][j] = (f32x4){0.f, 0.f, 0.f, 0.f};

  const int srow = tid >> 2;    // 0..63 (2 passes cover 128 rows)
  const int sseg = tid & 3;     // 32B segment within the 128B k-chunk

  for (int kc = 0; kc < 8; ++kc) {
    if (kc) __syncthreads();    // previous tile fully consumed
    // stage A chunk [128 rows x 32 k] f32 -> bf16 in LDS
#pragma unroll
    for (int p = 0; p < 2; ++p) {
      const int row = p * 64 + srow;
      // rows row0+row < 100096 <= N=120000: always in-bounds; garbage rows discarded later
      const float4* g = (const float4*)(sf + (size_t)(row0 + row) * 256 + kc * 32 + sseg * 8);
      const float4 v0 = g[0];
      const float4 v1 = g[1];
      uint4 pk;
      pk.x = f2bf2(v0.x, v0.y);
      pk.y = f2bf2(v0.z, v0.w);
      pk.z = f2bf2(v1.x, v1.y);
      pk.w = f2bf2(v1.z, v1.w);
      *(uint4*)&lA[row][sseg * 8] = pk;
    }
    __syncthreads();
#pragma unroll
    for (int rt = 0; rt < 8; ++rt) {
      bf16x8 fa = *(const bf16x8*)&lA[rt * 16 + l15][quad * 8];
      acc[rt][0] = __builtin_amdgcn_mfma_f32_16x16x32_bf16(fa, fb[kc][0], acc[rt][0], 0, 0, 0);
      acc[rt][1] = __builtin_amdgcn_mfma_f32_16x16x32_bf16(fa, fb[kc][1], acc[rt][1], 0, 0, 0);
    }
  }
  __syncthreads();  // done reading lA; smem becomes lC

  // write acc into LDS tile (row = quad*4+reg + rt*16, cols col0+l15, col0+16+l15)
  const int col0 = wave * 32;
#pragma unroll
  for (int rt = 0; rt < 8; ++rt) {
#pragma unroll
    for (int reg = 0; reg < 4; ++reg) {
      const int row = rt * 16 + quad * 4 + reg;
      const float inv = __builtin_amdgcn_rcpf(xn[row0 + row]);
      lC[row][col0 + l15]      = f2bf(acc[rt][0][reg] * inv);
      lC[row][col0 + 16 + l15] = f2bf(acc[rt][1][reg] * inv);
    }
  }
  __syncthreads();

  // coalesced out: 8 passes x 256 thr x 16B; full 256B rows
#pragma unroll
  for (int p = 0; p < 8; ++p) {
    const int i = p * 256 + tid;
    const int row = i >> 4;
    const int seg = i & 15;
    const int gr = row0 + row;
    if (gr < S_NUM)
      *(uint4*)(xb + (size_t)gr * 128 + seg * 8) = *(const uint4*)&lC[row][seg * 8];
  }
}

// K2: partition edges into NB buckets of GT targets each.
// Entry = (dst & 31) << 17 | src.
__launch_bounds__(512)
__global__ void k2_partition(const int* __restrict__ src_idx, const int* __restrict__ dst_idx,
                             int* __restrict__ gcursor, unsigned int* __restrict__ ebuf) {
  __shared__ int bcnt[NB];
  __shared__ int gbase[NB];
  const int tid = threadIdx.x;
  for (int c = blockIdx.x; c * CH < E_NUM; c += gridDim.x) {
    const int e0 = c * CH;
    const int e1 = (e0 + CH < E_NUM) ? (e0 + CH) : E_NUM;
    for (int i = tid; i < NB; i += 512) bcnt[i] = 0;
    __syncthreads();
    for (int e = e0 + tid; e < e1; e += 512)
      atomicAdd(&bcnt[dst_idx[e] >> 5], 1);
    __syncthreads();
    for (int i = tid; i < NB; i += 512) {
      const int cnt = bcnt[i];
      gbase[i] = (cnt > 0) ? atomicAdd(&gcursor[i], cnt) : 0;
      bcnt[i] = 0;  // reuse as rank counter
    }
    __syncthreads();
    for (int e = e0 + tid; e < e1; e += 512) {
      const int d = dst_idx[e];
      const int s = src_idx[e];
      const int b = d >> 5;
      const int r = atomicAdd(&bcnt[b], 1);
      const int pos = gbase[b] + r;
      if (pos < CAP)
        ebuf[(size_t)b * CAP + pos] = ((unsigned int)(d & 31) << 17) | (unsigned int)s;
    }
    __syncthreads();
  }
}

// K3: within-bucket counting sort -> per-target CSR.
__launch_bounds__(256)
__global__ void k3_sort(const int* __restrict__ gcursor, const unsigned int* __restrict__ ebuf,
                        unsigned int* __restrict__ ssorted, int* __restrict__ tstart,
                        int* __restrict__ tcnt) {
  __shared__ int hist[GT];
  __shared__ int scan[GT];
  __shared__ int cur[GT];
  const int b = blockIdx.x;
  const int tid = threadIdx.x;
  int n = gcursor[b];
  if (n > CAP) n = CAP;
  const unsigned int* eb = ebuf + (size_t)b * CAP;

  if (tid < GT) hist[tid] = 0;
  __syncthreads();
  for (int i = tid; i < n; i += 256) atomicAdd(&hist[eb[i] >> 17], 1);
  __syncthreads();
  if (tid == 0) {
    int run = 0;
#pragma unroll
    for (int i = 0; i < GT; ++i) { scan[i] = run; run += hist[i]; }
  }
  __syncthreads();
  if (tid < GT) {
    tstart[b * GT + tid] = b * CAP + scan[tid];
    tcnt[b * GT + tid] = hist[tid];
    cur[tid] = scan[tid];
  }
  __syncthreads();
  for (int i = tid; i < n; i += 256) {
    const unsigned int e = eb[i];
    const int dl = (int)(e >> 17);
    const int r = atomicAdd(&cur[dl], 1);
    ssorted[(size_t)b * CAP + r] = e & 0x1FFFFu;
  }
}

// K4: one wave per target; 8-deep independent gathers, register accumulators.
__launch_bounds__(256)
__global__ void k4_aggr(const int* __restrict__ tstart, const int* __restrict__ tcnt,
                        const unsigned int* __restrict__ ssorted,
                        const unsigned short* __restrict__ xb,
                        unsigned short* __restrict__ aggr) {
  const int wave = threadIdx.x >> 6, lane = threadIdx.x & 63;
  const int t = blockIdx.x * 4 + wave;  // grid = T/4, exact
  const int beg = tstart[t];
  const int cnt = tcnt[t];
  float a0 = 0.f, a1 = 0.f, b0 = 0.f, b1 = 0.f;
  int e = 0;
  for (; e + 8 <= cnt; e += 8) {
    int s[8];
#pragma unroll
    for (int j = 0; j < 8; ++j) s[j] = (int)ssorted[beg + e + j];
    unsigned int v[8];
#pragma unroll
    for (int j = 0; j < 8; ++j)
      v[j] = *(const unsigned int*)(xb + (size_t)s[j] * 128 + 2 * lane);
#pragma unroll
    for (int j = 0; j < 8; j += 2) {
      a0 += bflo(v[j]);     a1 += bfhi(v[j]);
      b0 += bflo(v[j + 1]); b1 += bfhi(v[j + 1]);
    }
  }
  for (; e < cnt; ++e) {
    const int s0 = (int)ssorted[beg + e];
    const unsigned int v0 = *(const unsigned int*)(xb + (size_t)s0 * 128 + 2 * lane);
    a0 += bflo(v0); a1 += bfhi(v0);
  }
  a0 += b0; a1 += b1;
  const float inv = (cnt > 0) ? __builtin_amdgcn_rcpf((float)cnt) : 0.f;
  *(unsigned int*)(aggr + (size_t)t * 128 + 2 * lane) = f2bf2(a0 * inv, a1 * inv);
}

// K6: out[T,128] = aggr[T,128](bf16) @ weight[128,128], fp32 LDS tiles
__global__ void k6_out(const unsigned short* __restrict__ aggr, const float* __restrict__ W,
                       float* __restrict__ out) {
  __shared__ float lA[16][128];
  __shared__ float lW[128][16];
  const int tid = threadIdx.x;
  const int tx = tid & 15, ty = tid >> 4;
  const int r0 = blockIdx.x * 16, c0 = blockIdx.y * 16;
#pragma unroll
  for (int i = 0; i < 4; ++i) {  // A: 16x128 bf16 = 1024 u32 words
    const int idx = i * 256 + tid;
    const int row = idx >> 6, wc = idx & 63;
    const unsigned int v = *(const unsigned int*)(aggr + (size_t)(r0 + row) * 128 + wc * 2);
    lA[row][wc * 2] = bflo(v);
    lA[row][wc * 2 + 1] = bfhi(v);
  }
#pragma unroll
  for (int i = 0; i < 8; ++i) {
    const int idx = i * 256 + tid;
    const int k = idx >> 4, c = idx & 15;
    lW[k][c] = W[(size_t)k * 128 + c0 + c];
  }
  __syncthreads();
  float acc = 0.f;
#pragma unroll
  for (int k = 0; k < 128; ++k) acc += lA[ty][k] * lW[k][tx];
  out[(size_t)(r0 + ty) * 128 + c0 + tx] = acc;
}

extern "C" void kernel_launch(void* const* d_in, const int* in_sizes, int n_in,
                              void* d_out, int out_size, void* d_ws, size_t ws_size,
                              hipStream_t stream) {
  const float* sf      = (const float*)d_in[0];   // [N,256] f32 (only rows < S used)
  const int*   src_idx = (const int*)d_in[1];     // [E]
  const int*   dst_idx = (const int*)d_in[2];     // [E]
  /* d_in[3] range_list: unused */
  const float* xn      = (const float*)d_in[4];   // [N]
  const float* embed   = (const float*)d_in[5];   // [256,128]
  const float* weight  = (const float*)d_in[6];   // [128,128]
  float* out = (float*)d_out;                     // [T,128] f32

  // workspace layout (16B-aligned), total ~38.6 MB
  char* w = (char*)d_ws;
  unsigned short* xb    = (unsigned short*)(w);              // 25,600,000
  unsigned short* embT  = (unsigned short*)(w + 25600000);   // 65,536
  int* gcursor          = (int*)(w + 25665536);              // 4,096 (625 used)
  unsigned int* ebuf    = (unsigned int*)(w + 25669632);     // 625*2560*4 = 6,400,000
  unsigned int* ssorted = (unsigned int*)(w + 32069632);     // 6,400,000
  int* tstart           = (int*)(w + 38469632);              // 80,000
  int* tcnt             = (int*)(w + 38549632);              // 80,000
  // aggr aliases ebuf (ebuf is dead after k3_sort)
  unsigned short* aggr  = (unsigned short*)(w + 25669632);   // 20000*128*2 = 5,120,000

  hipMemsetAsync(gcursor, 0, 4096, stream);
  k0_prep<<<128, 256, 0, stream>>>(embed, embT);
  k1_gemm<<<(S_NUM + 127) / 128, 256, 0, stream>>>(sf, xn, embT, xb);
  k2_partition<<<(E_NUM + CH - 1) / CH, 512, 0, stream>>>(src_idx, dst_idx, gcursor, ebuf);
  k3_sort<<<NB, 256, 0, stream>>>(gcursor, ebuf, ssorted, tstart, tcnt);
  k4_aggr<<<T_NUM / 4, 256, 0, stream>>>(tstart, tcnt, ssorted, xb, aggr);
  k6_out<<<dim3(T_NUM / 16, 8), 256, 0, stream>>>(aggr, weight, out);
}

// Round 6
// 266.758 us; speedup vs baseline: 4.0605x; 1.1825x over previous
//
#include <hip/hip_runtime.h>
#include <cstdint>
#include <cstddef>

#define S_NUM 100000
#define T_NUM 20000
#define E_NUM 1000000

#define NB   625      // buckets (T / GT)
#define GT   32       // targets per bucket
#define CAP  2560     // entries per bucket slot (mean 1600, sd ~40)
#define CH   2048     // edges per partition chunk

typedef __bf16 bf16x8 __attribute__((ext_vector_type(8)));
typedef float f32x4 __attribute__((ext_vector_type(4)));

__device__ __forceinline__ unsigned short f2bf(float f) {
  unsigned int u = __float_as_uint(f);
  u += 0x7fffu + ((u >> 16) & 1u);   // round-to-nearest-even
  return (unsigned short)(u >> 16);
}
__device__ __forceinline__ unsigned int f2bf2(float lo, float hi) {
  return (unsigned int)f2bf(lo) | ((unsigned int)f2bf(hi) << 16);
}
__device__ __forceinline__ float bflo(unsigned int v) { return __uint_as_float(v << 16); }
__device__ __forceinline__ float bfhi(unsigned int v) { return __uint_as_float(v & 0xffff0000u); }

// K0: embed [256,128] -> embT[128 n][256 k] bf16; weight [128,128] -> wT[128 n][128 k] bf16
__global__ void k0_prep(const float* __restrict__ embed, const float* __restrict__ weight,
                        unsigned short* __restrict__ embT, unsigned short* __restrict__ wT) {
  int idx = blockIdx.x * blockDim.x + threadIdx.x;  // 0..49151
  if (idx < 32768) {
    int n = idx & 127, k = idx >> 7;
    embT[n * 256 + k] = f2bf(embed[k * 128 + n]);
  } else {
    int j = idx - 32768;           // 0..16383
    int n = j & 127, k = j >> 7;
    wT[n * 128 + k] = f2bf(weight[k * 128 + n]);
  }
}

// K1: xb[S,128] bf16 = bf16( (sf[0:S,0:256] @ embed) / xn ).
// Full-K single-stage LDS tile (one barrier pair), B fragments in registers,
// LDS-transposed epilogue for coalesced 16B stores.
__launch_bounds__(256)
__global__ void k1_gemm(const float* __restrict__ sf, const float* __restrict__ xn,
                        const unsigned short* __restrict__ embT,
                        unsigned short* __restrict__ xb) {
  // staging tile [128][264] shorts (528B rows, 2-way-free banks) = 67,584 B;
  // epilogue reuses it as [128][136].
  __shared__ __align__(16) unsigned char smem[128 * 264 * 2];
  unsigned short (*lA)[264] = (unsigned short (*)[264])smem;
  unsigned short (*lC)[136] = (unsigned short (*)[136])smem;

  const int tid = threadIdx.x;
  const int wave = tid >> 6;
  const int lane = tid & 63;
  const int quad = lane >> 4;
  const int l15 = lane & 15;
  const int row0 = blockIdx.x * 128;

  // Preload B fragments for this wave's 32 output cols: fb[kc][ct]
  bf16x8 fb[8][2];
#pragma unroll
  for (int kc = 0; kc < 8; ++kc)
#pragma unroll
    for (int ct = 0; ct < 2; ++ct) {
      const int n = wave * 32 + ct * 16 + l15;
      fb[kc][ct] = *(const bf16x8*)(embT + (size_t)n * 256 + kc * 32 + quad * 8);
    }

  // Stage full [128 x 256] A tile, f32 -> bf16, coalesced 32B/thread/iter
#pragma unroll
  for (int i = 0; i < 16; ++i) {
    const int idx = i * 256 + tid;        // 0..4095
    const int row = idx >> 5;             // 0..127
    const int seg = idx & 31;             // 8-float segment
    // rows row0+row <= 100095 < N=120000: always in-bounds (junk rows dropped at store)
    const float4* g = (const float4*)(sf + (size_t)(row0 + row) * 256 + seg * 8);
    const float4 v0 = g[0];
    const float4 v1 = g[1];
    uint4 pk;
    pk.x = f2bf2(v0.x, v0.y);
    pk.y = f2bf2(v0.z, v0.w);
    pk.z = f2bf2(v1.x, v1.y);
    pk.w = f2bf2(v1.z, v1.w);
    *(uint4*)&lA[row][seg * 8] = pk;
  }
  __syncthreads();

  f32x4 acc[8][2];
#pragma unroll
  for (int i = 0; i < 8; ++i)
#pragma unroll
    for (int j = 0; j < 2; ++j) acc[i][j] = (f32x4){0.f, 0.f, 0.f, 0.f};

#pragma unroll
  for (int kc = 0; kc < 8; ++kc)
#pragma unroll
    for (int rt = 0; rt < 8; ++rt) {
      bf16x8 fa = *(const bf16x8*)&lA[rt * 16 + l15][kc * 32 + quad * 8];
      acc[rt][0] = __builtin_amdgcn_mfma_f32_16x16x32_bf16(fa, fb[kc][0], acc[rt][0], 0, 0, 0);
      acc[rt][1] = __builtin_amdgcn_mfma_f32_16x16x32_bf16(fa, fb[kc][1], acc[rt][1], 0, 0, 0);
    }
  __syncthreads();  // done reading lA; smem becomes lC

  // write acc into LDS tile (row = rt*16 + quad*4+reg, cols col0+l15, col0+16+l15)
  const int col0 = wave * 32;
#pragma unroll
  for (int rt = 0; rt < 8; ++rt) {
#pragma unroll
    for (int reg = 0; reg < 4; ++reg) {
      const int row = rt * 16 + quad * 4 + reg;
      const float inv = __builtin_amdgcn_rcpf(xn[row0 + row]);
      lC[row][col0 + l15]      = f2bf(acc[rt][0][reg] * inv);
      lC[row][col0 + 16 + l15] = f2bf(acc[rt][1][reg] * inv);
    }
  }
  __syncthreads();

  // coalesced out: 8 passes x 256 thr x 16B; full 256B rows
#pragma unroll
  for (int p = 0; p < 8; ++p) {
    const int i = p * 256 + tid;
    const int row = i >> 4;
    const int seg = i & 15;
    const int gr = row0 + row;
    if (gr < S_NUM)
      *(uint4*)(xb + (size_t)gr * 128 + seg * 8) = *(const uint4*)&lC[row][seg * 8];
  }
}

// K2: partition edges into NB buckets of GT targets each.
// Entry = (dst & 31) << 17 | src.
__launch_bounds__(512)
__global__ void k2_partition(const int* __restrict__ src_idx, const int* __restrict__ dst_idx,
                             int* __restrict__ gcursor, unsigned int* __restrict__ ebuf) {
  __shared__ int bcnt[NB];
  __shared__ int gbase[NB];
  const int tid = threadIdx.x;
  for (int c = blockIdx.x; c * CH < E_NUM; c += gridDim.x) {
    const int e0 = c * CH;
    const int e1 = (e0 + CH < E_NUM) ? (e0 + CH) : E_NUM;
    for (int i = tid; i < NB; i += 512) bcnt[i] = 0;
    __syncthreads();
    for (int e = e0 + tid; e < e1; e += 512)
      atomicAdd(&bcnt[dst_idx[e] >> 5], 1);
    __syncthreads();
    for (int i = tid; i < NB; i += 512) {
      const int cnt = bcnt[i];
      gbase[i] = (cnt > 0) ? atomicAdd(&gcursor[i], cnt) : 0;
      bcnt[i] = 0;  // reuse as rank counter
    }
    __syncthreads();
    for (int e = e0 + tid; e < e1; e += 512) {
      const int d = dst_idx[e];
      const int s = src_idx[e];
      const int b = d >> 5;
      const int r = atomicAdd(&bcnt[b], 1);
      const int pos = gbase[b] + r;
      if (pos < CAP)
        ebuf[(size_t)b * CAP + pos] = ((unsigned int)(d & 31) << 17) | (unsigned int)s;
    }
    __syncthreads();
  }
}

// K3 (fused sort + aggregate + output GEMM). One block (512 thr, 8 waves) per bucket.
// Phase A: counting-sort bucket's edges into LDS. Phase B: wave-per-target mean
// aggregation (8-deep gather ILP) -> P tile (packed bf16) in LDS.
// Phase C: out[32x128] = P @ W via MFMA, direct f32 stores.
__launch_bounds__(512)
__global__ void k3_fused(const int* __restrict__ gcursor, const unsigned int* __restrict__ ebuf,
                         const unsigned short* __restrict__ xb,
                         const unsigned short* __restrict__ wT,
                         float* __restrict__ out) {
  __shared__ unsigned int sls[CAP];       // sorted src list (10,240 B)
  __shared__ int hist[GT], scn[GT], cur[GT];
  __shared__ unsigned int Pu[GT][68];     // packed bf16 pairs, padded (8,704 B)
  const int b = blockIdx.x;
  const int tid = threadIdx.x;
  const int wave = tid >> 6, lane = tid & 63;
  const int quad = lane >> 4, l15 = lane & 15;

  int n = gcursor[b];
  if (n > CAP) n = CAP;
  const unsigned int* eb = ebuf + (size_t)b * CAP;

  // Phase A: sort into LDS
  if (tid < GT) hist[tid] = 0;
  __syncthreads();
  for (int i = tid; i < n; i += 512) atomicAdd(&hist[eb[i] >> 17], 1);
  __syncthreads();
  if (tid == 0) {
    int run = 0;
#pragma unroll
    for (int i = 0; i < GT; ++i) { scn[i] = run; run += hist[i]; }
  }
  __syncthreads();
  if (tid < GT) cur[tid] = scn[tid];
  __syncthreads();
  for (int i = tid; i < n; i += 512) {
    const unsigned int e = eb[i];
    const int r = atomicAdd(&cur[e >> 17], 1);
    sls[r] = e & 0x1FFFFu;
  }
  __syncthreads();

  // Phase B: wave-per-target aggregation from LDS-sorted list
#pragma unroll
  for (int rep = 0; rep < 4; ++rep) {
    const int tl = wave * 4 + rep;
    const int beg = scn[tl];
    const int c = hist[tl];
    float a0 = 0.f, a1 = 0.f, b0 = 0.f, b1 = 0.f;
    int e = 0;
    for (; e + 8 <= c; e += 8) {
      int s[8];
#pragma unroll
      for (int j = 0; j < 8; ++j) s[j] = (int)sls[beg + e + j];  // LDS broadcast
      unsigned int v[8];
#pragma unroll
      for (int j = 0; j < 8; ++j)
        v[j] = *(const unsigned int*)(xb + (size_t)s[j] * 128 + 2 * lane);
#pragma unroll
      for (int j = 0; j < 8; j += 2) {
        a0 += bflo(v[j]);     a1 += bfhi(v[j]);
        b0 += bflo(v[j + 1]); b1 += bfhi(v[j + 1]);
      }
    }
    for (; e < c; ++e) {
      const int s0 = (int)sls[beg + e];
      const unsigned int v0 = *(const unsigned int*)(xb + (size_t)s0 * 128 + 2 * lane);
      a0 += bflo(v0); a1 += bfhi(v0);
    }
    a0 += b0; a1 += b1;
    const float inv = (c > 0) ? __builtin_amdgcn_rcpf((float)c) : 0.f;
    Pu[tl][lane] = f2bf2(a0 * inv, a1 * inv);
  }
  __syncthreads();

  // Phase C: out[b*32 .. b*32+31][0..127] = P @ W (MFMA 16x16x32, 2 m-tiles, 4 k-chunks)
  const int ncol = wave * 16 + l15;
  bf16x8 wb[4];
#pragma unroll
  for (int kc = 0; kc < 4; ++kc)
    wb[kc] = *(const bf16x8*)(wT + (size_t)ncol * 128 + kc * 32 + quad * 8);
  f32x4 o0 = (f32x4){0.f, 0.f, 0.f, 0.f};
  f32x4 o1 = (f32x4){0.f, 0.f, 0.f, 0.f};
#pragma unroll
  for (int kc = 0; kc < 4; ++kc) {
    bf16x8 p0 = *(const bf16x8*)((const unsigned short*)&Pu[l15][0] + kc * 32 + quad * 8);
    bf16x8 p1 = *(const bf16x8*)((const unsigned short*)&Pu[16 + l15][0] + kc * 32 + quad * 8);
    o0 = __builtin_amdgcn_mfma_f32_16x16x32_bf16(p0, wb[kc], o0, 0, 0, 0);
    o1 = __builtin_amdgcn_mfma_f32_16x16x32_bf16(p1, wb[kc], o1, 0, 0, 0);
  }
#pragma unroll
  for (int reg = 0; reg < 4; ++reg) {
    out[((size_t)b * 32 + quad * 4 + reg) * 128 + ncol]      = o0[reg];
    out[((size_t)b * 32 + 16 + quad * 4 + reg) * 128 + ncol] = o1[reg];
  }
}

extern "C" void kernel_launch(void* const* d_in, const int* in_sizes, int n_in,
                              void* d_out, int out_size, void* d_ws, size_t ws_size,
                              hipStream_t stream) {
  const float* sf      = (const float*)d_in[0];   // [N,256] f32 (only rows < S used)
  const int*   src_idx = (const int*)d_in[1];     // [E]
  const int*   dst_idx = (const int*)d_in[2];     // [E]
  /* d_in[3] range_list: unused */
  const float* xn      = (const float*)d_in[4];   // [N]
  const float* embed   = (const float*)d_in[5];   // [256,128]
  const float* weight  = (const float*)d_in[6];   // [128,128]
  float* out = (float*)d_out;                     // [T,128] f32

  // workspace layout (16B-aligned), total ~32.1 MB
  char* w = (char*)d_ws;
  unsigned short* xb   = (unsigned short*)(w);               // 25,600,000
  unsigned short* embT = (unsigned short*)(w + 25600000);    // 65,536
  unsigned short* wT   = (unsigned short*)(w + 25665536);    // 32,768
  int* gcursor         = (int*)(w + 25698304);               // 4,096 (625 used)
  unsigned int* ebuf   = (unsigned int*)(w + 25702400);      // 625*2560*4 = 6,400,000

  hipMemsetAsync(gcursor, 0, 4096, stream);
  k0_prep<<<192, 256, 0, stream>>>(embed, weight, embT, wT);
  k1_gemm<<<(S_NUM + 127) / 128, 256, 0, stream>>>(sf, xn, embT, xb);
  k2_partition<<<(E_NUM + CH - 1) / CH, 512, 0, stream>>>(src_idx, dst_idx, gcursor, ebuf);
  k3_fused<<<NB, 512, 0, stream>>>(gcursor, ebuf, xb, wT, out);
}

// Round 7
// 254.967 us; speedup vs baseline: 4.2482x; 1.0462x over previous
//
#include <hip/hip_runtime.h>
#include <cstdint>
#include <cstddef>

#define S_NUM 100000
#define T_NUM 20000
#define E_NUM 1000000

#define NB   625      // buckets (T / GT)
#define GT   32       // targets per bucket
#define CAP  2560     // entries per bucket slot (mean 1600, max ~1750)
#define CH   4096     // edges per partition chunk
#define KB2  245      // number of k2-branch blocks (= chunks)
#define KB1  782      // number of k1-branch blocks (= ceil(S/128))

typedef __bf16 bf16x8 __attribute__((ext_vector_type(8)));
typedef float f32x4 __attribute__((ext_vector_type(4)));

__device__ __forceinline__ unsigned short f2bf(float f) {
  unsigned int u = __float_as_uint(f);
  u += 0x7fffu + ((u >> 16) & 1u);   // round-to-nearest-even
  return (unsigned short)(u >> 16);
}
__device__ __forceinline__ unsigned int f2bf2(float lo, float hi) {
  return (unsigned int)f2bf(lo) | ((unsigned int)f2bf(hi) << 16);
}
__device__ __forceinline__ float bflo(unsigned int v) { return __uint_as_float(v << 16); }
__device__ __forceinline__ float bfhi(unsigned int v) { return __uint_as_float(v & 0xffff0000u); }

// K12: horizontally-fused kernel.
//   blocks [0, KB2):        edge partition (latency/atomic-bound)
//   blocks [KB2, KB2+KB1):  embed GEMM (MFMA/HBM-bound)
// The two populations co-reside on CUs; k2's stalls hide under k1's work.
__launch_bounds__(512)
__global__ void k12_fused(const float* __restrict__ sf, const float* __restrict__ xn,
                          const float* __restrict__ embed, unsigned short* __restrict__ xb,
                          const int* __restrict__ src_idx, const int* __restrict__ dst_idx,
                          int* __restrict__ gcursor, unsigned int* __restrict__ ebuf) {
  __shared__ __align__(16) unsigned char smem[128 * 264 * 2];  // 67,584 B
  const int tid = threadIdx.x;

  if (blockIdx.x < KB2) {
    // ---- k2 branch: partition one CH-edge chunk into NB buckets ----
    int* bcnt  = (int*)smem;                 // NB ints
    int* gbase = (int*)(smem + 2560);        // NB ints
    const int e0 = blockIdx.x * CH;
    const int e1 = (e0 + CH < E_NUM) ? (e0 + CH) : E_NUM;
    for (int i = tid; i < NB; i += 512) bcnt[i] = 0;
    __syncthreads();
    for (int e = e0 + tid; e < e1; e += 512)
      atomicAdd(&bcnt[dst_idx[e] >> 5], 1);
    __syncthreads();
    for (int i = tid; i < NB; i += 512) {
      const int cnt = bcnt[i];
      gbase[i] = (cnt > 0) ? atomicAdd(&gcursor[i], cnt) : 0;
      bcnt[i] = 0;  // reuse as rank counter
    }
    __syncthreads();
    for (int e = e0 + tid; e < e1; e += 512) {
      const int d = dst_idx[e];
      const int s = src_idx[e];
      const int b = d >> 5;
      const int r = atomicAdd(&bcnt[b], 1);
      const int pos = gbase[b] + r;
      if (pos < CAP)
        ebuf[(size_t)b * CAP + pos] = ((unsigned int)(d & 31) << 17) | (unsigned int)s;
    }
    return;
  }

  // ---- k1 branch: xb[S,128] = bf16((sf @ embed) / xn), 128-row tile ----
  unsigned short (*lA)[264] = (unsigned short (*)[264])smem;
  unsigned short (*lC)[136] = (unsigned short (*)[136])smem;
  const int wave = tid >> 6;      // 0..7, each wave owns 16 output cols
  const int lane = tid & 63;
  const int quad = lane >> 4;
  const int l15 = lane & 15;
  const int row0 = (blockIdx.x - KB2) * 128;
  const int col0 = wave * 16;

  // B fragments straight from embed f32 (128 KB, L2-hot): fb[kc][j] =
  // embed[(kc*32+quad*8+j)*128 + col0+l15]
  bf16x8 fb[8];
#pragma unroll
  for (int kc = 0; kc < 8; ++kc) {
    union { unsigned short h[8]; bf16x8 v; } u;
#pragma unroll
    for (int j = 0; j < 8; ++j)
      u.h[j] = f2bf(embed[(size_t)(kc * 32 + quad * 8 + j) * 128 + col0 + l15]);
    fb[kc] = u.v;
  }

  // Stage full [128 x 256] A tile, f32 -> bf16, 32B/thread/iter coalesced
#pragma unroll
  for (int i = 0; i < 8; ++i) {
    const int idx = i * 512 + tid;        // 0..4095
    const int row = idx >> 5;             // 0..127
    const int seg = idx & 31;             // 8-float segment
    // rows row0+row <= 100095 < N=120000: in-bounds (junk rows dropped at store)
    const float4* g = (const float4*)(sf + (size_t)(row0 + row) * 256 + seg * 8);
    const float4 v0 = g[0];
    const float4 v1 = g[1];
    uint4 pk;
    pk.x = f2bf2(v0.x, v0.y);
    pk.y = f2bf2(v0.z, v0.w);
    pk.z = f2bf2(v1.x, v1.y);
    pk.w = f2bf2(v1.z, v1.w);
    *(uint4*)&lA[row][seg * 8] = pk;
  }
  __syncthreads();

  f32x4 acc[8];
#pragma unroll
  for (int i = 0; i < 8; ++i) acc[i] = (f32x4){0.f, 0.f, 0.f, 0.f};

#pragma unroll
  for (int kc = 0; kc < 8; ++kc)
#pragma unroll
    for (int rt = 0; rt < 8; ++rt) {
      bf16x8 fa = *(const bf16x8*)&lA[rt * 16 + l15][kc * 32 + quad * 8];
      acc[rt] = __builtin_amdgcn_mfma_f32_16x16x32_bf16(fa, fb[kc], acc[rt], 0, 0, 0);
    }
  __syncthreads();  // done reading lA; smem becomes lC

  // acc -> LDS (row = rt*16+quad*4+reg, col = col0+l15), scaled by 1/xn
#pragma unroll
  for (int rt = 0; rt < 8; ++rt) {
#pragma unroll
    for (int reg = 0; reg < 4; ++reg) {
      const int row = rt * 16 + quad * 4 + reg;
      const float inv = __builtin_amdgcn_rcpf(xn[row0 + row]);
      lC[row][col0 + l15] = f2bf(acc[rt][reg] * inv);
    }
  }
  __syncthreads();

  // coalesced out: 4 passes x 512 thr x 16B = full 256B rows
#pragma unroll
  for (int p = 0; p < 4; ++p) {
    const int i = p * 512 + tid;
    const int row = i >> 4;
    const int seg = i & 15;
    const int gr = row0 + row;
    if (gr < S_NUM)
      *(uint4*)(xb + (size_t)gr * 128 + seg * 8) = *(const uint4*)&lC[row][seg * 8];
  }
}

// K3 (fused sort + aggregate + output GEMM). One block (512 thr, 8 waves) per bucket.
__launch_bounds__(512)
__global__ void k3_fused(const int* __restrict__ gcursor, const unsigned int* __restrict__ ebuf,
                         const unsigned short* __restrict__ xb,
                         const float* __restrict__ weight,
                         float* __restrict__ out) {
  __shared__ unsigned int sls[CAP];       // sorted src list (10,240 B)
  __shared__ int hist[GT], scn[GT], cur[GT];
  __shared__ unsigned int Pu[GT][68];     // packed bf16 pairs, padded
  const int b = blockIdx.x;
  const int tid = threadIdx.x;
  const int wave = tid >> 6, lane = tid & 63;
  const int quad = lane >> 4, l15 = lane & 15;

  int n = gcursor[b];
  if (n > CAP) n = CAP;
  const unsigned int* eb = ebuf + (size_t)b * CAP;

  // Phase A: counting-sort into LDS
  if (tid < GT) hist[tid] = 0;
  __syncthreads();
  for (int i = tid; i < n; i += 512) atomicAdd(&hist[eb[i] >> 17], 1);
  __syncthreads();
  if (tid == 0) {
    int run = 0;
#pragma unroll
    for (int i = 0; i < GT; ++i) { scn[i] = run; run += hist[i]; }
  }
  __syncthreads();
  if (tid < GT) cur[tid] = scn[tid];
  __syncthreads();
  for (int i = tid; i < n; i += 512) {
    const unsigned int e = eb[i];
    const int r = atomicAdd(&cur[e >> 17], 1);
    sls[r] = e & 0x1FFFFu;
  }
  __syncthreads();

  // Phase B: wave-per-target mean aggregation, 16-deep gather ILP
#pragma unroll
  for (int rep = 0; rep < 4; ++rep) {
    const int tl = wave * 4 + rep;
    const int beg = scn[tl];
    const int c = hist[tl];
    float a0 = 0.f, a1 = 0.f, b0 = 0.f, b1 = 0.f;
    int e = 0;
    for (; e + 16 <= c; e += 16) {
      int s[16];
#pragma unroll
      for (int j = 0; j < 16; ++j) s[j] = (int)sls[beg + e + j];  // LDS broadcast
      unsigned int v[16];
#pragma unroll
      for (int j = 0; j < 16; ++j)
        v[j] = *(const unsigned int*)(xb + (size_t)s[j] * 128 + 2 * lane);
#pragma unroll
      for (int j = 0; j < 16; j += 2) {
        a0 += bflo(v[j]);     a1 += bfhi(v[j]);
        b0 += bflo(v[j + 1]); b1 += bfhi(v[j + 1]);
      }
    }
    for (; e + 4 <= c; e += 4) {
      int s[4];
#pragma unroll
      for (int j = 0; j < 4; ++j) s[j] = (int)sls[beg + e + j];
      unsigned int v[4];
#pragma unroll
      for (int j = 0; j < 4; ++j)
        v[j] = *(const unsigned int*)(xb + (size_t)s[j] * 128 + 2 * lane);
      a0 += bflo(v[0]); a1 += bfhi(v[0]);
      b0 += bflo(v[1]); b1 += bfhi(v[1]);
      a0 += bflo(v[2]); a1 += bfhi(v[2]);
      b0 += bflo(v[3]); b1 += bfhi(v[3]);
    }
    for (; e < c; ++e) {
      const int s0 = (int)sls[beg + e];
      const unsigned int v0 = *(const unsigned int*)(xb + (size_t)s0 * 128 + 2 * lane);
      a0 += bflo(v0); a1 += bfhi(v0);
    }
    a0 += b0; a1 += b1;
    const float inv = (c > 0) ? __builtin_amdgcn_rcpf((float)c) : 0.f;
    Pu[tl][lane] = f2bf2(a0 * inv, a1 * inv);
  }
  __syncthreads();

  // Phase C: out[b*32..b*32+31][:] = P @ W via MFMA; W fragments from f32 weight (L2-hot)
  const int ncol = wave * 16 + l15;
  bf16x8 wb[4];
#pragma unroll
  for (int kc = 0; kc < 4; ++kc) {
    union { unsigned short h[8]; bf16x8 v; } u;
#pragma unroll
    for (int j = 0; j < 8; ++j)
      u.h[j] = f2bf(weight[(size_t)(kc * 32 + quad * 8 + j) * 128 + ncol]);
    wb[kc] = u.v;
  }
  f32x4 o0 = (f32x4){0.f, 0.f, 0.f, 0.f};
  f32x4 o1 = (f32x4){0.f, 0.f, 0.f, 0.f};
#pragma unroll
  for (int kc = 0; kc < 4; ++kc) {
    bf16x8 p0 = *(const bf16x8*)((const unsigned short*)&Pu[l15][0] + kc * 32 + quad * 8);
    bf16x8 p1 = *(const bf16x8*)((const unsigned short*)&Pu[16 + l15][0] + kc * 32 + quad * 8);
    o0 = __builtin_amdgcn_mfma_f32_16x16x32_bf16(p0, wb[kc], o0, 0, 0, 0);
    o1 = __builtin_amdgcn_mfma_f32_16x16x32_bf16(p1, wb[kc], o1, 0, 0, 0);
  }
#pragma unroll
  for (int reg = 0; reg < 4; ++reg) {
    out[((size_t)b * 32 + quad * 4 + reg) * 128 + ncol]      = o0[reg];
    out[((size_t)b * 32 + 16 + quad * 4 + reg) * 128 + ncol] = o1[reg];
  }
}

extern "C" void kernel_launch(void* const* d_in, const int* in_sizes, int n_in,
                              void* d_out, int out_size, void* d_ws, size_t ws_size,
                              hipStream_t stream) {
  const float* sf      = (const float*)d_in[0];   // [N,256] f32 (only rows < S used)
  const int*   src_idx = (const int*)d_in[1];     // [E]
  const int*   dst_idx = (const int*)d_in[2];     // [E]
  /* d_in[3] range_list: unused */
  const float* xn      = (const float*)d_in[4];   // [N]
  const float* embed   = (const float*)d_in[5];   // [256,128]
  const float* weight  = (const float*)d_in[6];   // [128,128]
  float* out = (float*)d_out;                     // [T,128] f32

  // workspace layout (16B-aligned), total ~32.0 MB
  char* w = (char*)d_ws;
  unsigned short* xb = (unsigned short*)(w);            // 25,600,000
  int* gcursor       = (int*)(w + 25600000);            // 4,096 (625 used)
  unsigned int* ebuf = (unsigned int*)(w + 25604096);   // 625*2560*4 = 6,400,000

  hipMemsetAsync(gcursor, 0, 4096, stream);
  k12_fused<<<KB2 + KB1, 512, 0, stream>>>(sf, xn, embed, xb, src_idx, dst_idx, gcursor, ebuf);
  k3_fused<<<NB, 512, 0, stream>>>(gcursor, ebuf, xb, weight, out);
}

// Round 8
// 246.637 us; speedup vs baseline: 4.3917x; 1.0338x over previous
//
#include <hip/hip_runtime.h>
#include <cstdint>
#include <cstddef>

#define S_NUM 100000
#define T_NUM 20000
#define E_NUM 1000000

#define NB   1250     // buckets (T / GT)
#define GT   16       // targets per bucket
#define CAP  1280     // entries per bucket slot (mean 800, max ~950)
#define CH   4096     // edges per partition chunk
#define KB2  245      // k2-branch blocks (= chunks)
#define KB1  1563     // k1-branch blocks (= ceil(S/64))

typedef __bf16 bf16x8 __attribute__((ext_vector_type(8)));
typedef float f32x4 __attribute__((ext_vector_type(4)));

__device__ __forceinline__ unsigned short f2bf(float f) {
  unsigned int u = __float_as_uint(f);
  u += 0x7fffu + ((u >> 16) & 1u);   // round-to-nearest-even
  return (unsigned short)(u >> 16);
}
__device__ __forceinline__ unsigned int f2bf2(float lo, float hi) {
  return (unsigned int)f2bf(lo) | ((unsigned int)f2bf(hi) << 16);
}
__device__ __forceinline__ float bflo(unsigned int v) { return __uint_as_float(v << 16); }
__device__ __forceinline__ float bfhi(unsigned int v) { return __uint_as_float(v & 0xffff0000u); }

// K12: horizontally-fused kernel.
//   blocks [0, KB2):        edge partition into NB buckets (latency/atomic-bound)
//   blocks [KB2, KB2+KB1):  embed GEMM, 64-row tiles (MFMA/HBM-bound)
// 64-row tile => 37.9 KB LDS => 4 blocks/CU (occupancy fix vs r7's 2).
// Staging stride 296 shorts = 148 dw == 20 mod 32: replicates r4's measured
// 0-conflict fragment-read pattern (r7's 264-short stride == 4 mod 32 gave 1.9M).
__launch_bounds__(512)
__global__ void k12_fused(const float* __restrict__ sf, const float* __restrict__ xn,
                          const float* __restrict__ embed, unsigned short* __restrict__ xb,
                          const int* __restrict__ src_idx, const int* __restrict__ dst_idx,
                          int* __restrict__ gcursor, unsigned int* __restrict__ ebuf) {
  __shared__ __align__(16) unsigned char smem[64 * 296 * 2];  // 37,888 B
  const int tid = threadIdx.x;

  if (blockIdx.x < KB2) {
    // ---- k2 branch: partition one CH-edge chunk into NB buckets ----
    int* bcnt  = (int*)smem;                 // NB ints (5,000 B)
    int* gbase = (int*)(smem + 5120);        // NB ints
    const int e0 = blockIdx.x * CH;
    const int e1 = (e0 + CH < E_NUM) ? (e0 + CH) : E_NUM;
    for (int i = tid; i < NB; i += 512) bcnt[i] = 0;
    __syncthreads();
    for (int e = e0 + tid; e < e1; e += 512)
      atomicAdd(&bcnt[dst_idx[e] >> 4], 1);
    __syncthreads();
    for (int i = tid; i < NB; i += 512) {
      const int cnt = bcnt[i];
      gbase[i] = (cnt > 0) ? atomicAdd(&gcursor[i], cnt) : 0;
      bcnt[i] = 0;  // reuse as rank counter
    }
    __syncthreads();
    for (int e = e0 + tid; e < e1; e += 512) {
      const int d = dst_idx[e];
      const int s = src_idx[e];
      const int b = d >> 4;
      const int r = atomicAdd(&bcnt[b], 1);
      const int pos = gbase[b] + r;
      if (pos < CAP)
        ebuf[(size_t)b * CAP + pos] = ((unsigned int)(d & 15) << 17) | (unsigned int)s;
    }
    return;
  }

  // ---- k1 branch: xb[64-row tile] = bf16((sf @ embed) / xn) ----
  unsigned short (*lA)[296] = (unsigned short (*)[296])smem;
  unsigned short (*lC)[136] = (unsigned short (*)[136])smem;
  const int wave = tid >> 6;      // 0..7, each wave owns 16 output cols
  const int lane = tid & 63;
  const int quad = lane >> 4;
  const int l15 = lane & 15;
  const int row0 = (blockIdx.x - KB2) * 64;
  const int col0 = wave * 16;

  // B fragments straight from embed f32 (128 KB, L2-hot)
  bf16x8 fb[8];
#pragma unroll
  for (int kc = 0; kc < 8; ++kc) {
    union { unsigned short h[8]; bf16x8 v; } u;
#pragma unroll
    for (int j = 0; j < 8; ++j)
      u.h[j] = f2bf(embed[(size_t)(kc * 32 + quad * 8 + j) * 128 + col0 + l15]);
    fb[kc] = u.v;
  }

  // Stage [64 x 256] A tile, f32 -> bf16, 32B/thread/iter coalesced
#pragma unroll
  for (int i = 0; i < 4; ++i) {
    const int idx = i * 512 + tid;        // 0..2047
    const int row = idx >> 5;             // 0..63
    const int seg = idx & 31;             // 8-float segment
    // rows row0+row <= 100031 < N=120000: in-bounds (junk rows dropped at store)
    const float4* g = (const float4*)(sf + (size_t)(row0 + row) * 256 + seg * 8);
    const float4 v0 = g[0];
    const float4 v1 = g[1];
    uint4 pk;
    pk.x = f2bf2(v0.x, v0.y);
    pk.y = f2bf2(v0.z, v0.w);
    pk.z = f2bf2(v1.x, v1.y);
    pk.w = f2bf2(v1.z, v1.w);
    *(uint4*)&lA[row][seg * 8] = pk;
  }
  __syncthreads();

  f32x4 acc[4];
#pragma unroll
  for (int i = 0; i < 4; ++i) acc[i] = (f32x4){0.f, 0.f, 0.f, 0.f};

#pragma unroll
  for (int kc = 0; kc < 8; ++kc)
#pragma unroll
    for (int rt = 0; rt < 4; ++rt) {
      bf16x8 fa = *(const bf16x8*)&lA[rt * 16 + l15][kc * 32 + quad * 8];
      acc[rt] = __builtin_amdgcn_mfma_f32_16x16x32_bf16(fa, fb[kc], acc[rt], 0, 0, 0);
    }
  __syncthreads();  // done reading lA; smem becomes lC

  // acc -> LDS (row = rt*16+quad*4+reg, col = col0+l15), scaled by 1/xn
#pragma unroll
  for (int rt = 0; rt < 4; ++rt) {
#pragma unroll
    for (int reg = 0; reg < 4; ++reg) {
      const int row = rt * 16 + quad * 4 + reg;
      const float inv = __builtin_amdgcn_rcpf(xn[row0 + row]);
      lC[row][col0 + l15] = f2bf(acc[rt][reg] * inv);
    }
  }
  __syncthreads();

  // coalesced out: 2 passes x 512 thr x 16B = full 256B rows
#pragma unroll
  for (int p = 0; p < 2; ++p) {
    const int i = p * 512 + tid;
    const int row = i >> 4;
    const int seg = i & 15;
    const int gr = row0 + row;
    if (gr < S_NUM)
      *(uint4*)(xb + (size_t)gr * 128 + seg * 8) = *(const uint4*)&lC[row][seg * 8];
  }
}

// K3 (fused sort + aggregate + output GEMM). One block (512 thr, 8 waves)
// per 16-target bucket; 1250 blocks (~4.9/CU) for latency hiding.
__launch_bounds__(512)
__global__ void k3_fused(const int* __restrict__ gcursor, const unsigned int* __restrict__ ebuf,
                         const unsigned short* __restrict__ xb,
                         const float* __restrict__ weight,
                         float* __restrict__ out) {
  __shared__ unsigned int sls[CAP];       // sorted src list (5,120 B)
  __shared__ int hist[GT], scn[GT], cur[GT];
  __shared__ unsigned int Pu[GT][68];     // packed bf16 pairs, padded (4,352 B)
  const int b = blockIdx.x;
  const int tid = threadIdx.x;
  const int wave = tid >> 6, lane = tid & 63;
  const int quad = lane >> 4, l15 = lane & 15;

  int n = gcursor[b];
  if (n > CAP) n = CAP;
  const unsigned int* eb = ebuf + (size_t)b * CAP;

  // Phase A: counting-sort into LDS
  if (tid < GT) hist[tid] = 0;
  __syncthreads();
  for (int i = tid; i < n; i += 512) atomicAdd(&hist[eb[i] >> 17], 1);
  __syncthreads();
  if (tid == 0) {
    int run = 0;
#pragma unroll
    for (int i = 0; i < GT; ++i) { scn[i] = run; run += hist[i]; }
  }
  __syncthreads();
  if (tid < GT) cur[tid] = scn[tid];
  __syncthreads();
  for (int i = tid; i < n; i += 512) {
    const unsigned int e = eb[i];
    const int r = atomicAdd(&cur[e >> 17], 1);
    sls[r] = e & 0x1FFFFu;
  }
  __syncthreads();

  // Phase B: wave-per-target mean aggregation, 16-deep gather ILP
#pragma unroll
  for (int rep = 0; rep < 2; ++rep) {
    const int tl = wave * 2 + rep;
    const int beg = scn[tl];
    const int c = hist[tl];
    float a0 = 0.f, a1 = 0.f, b0 = 0.f, b1 = 0.f;
    int e = 0;
    for (; e + 16 <= c; e += 16) {
      int s[16];
#pragma unroll
      for (int j = 0; j < 16; ++j) s[j] = (int)sls[beg + e + j];  // LDS broadcast
      unsigned int v[16];
#pragma unroll
      for (int j = 0; j < 16; ++j)
        v[j] = *(const unsigned int*)(xb + (size_t)s[j] * 128 + 2 * lane);
#pragma unroll
      for (int j = 0; j < 16; j += 2) {
        a0 += bflo(v[j]);     a1 += bfhi(v[j]);
        b0 += bflo(v[j + 1]); b1 += bfhi(v[j + 1]);
      }
    }
    for (; e + 4 <= c; e += 4) {
      int s[4];
#pragma unroll
      for (int j = 0; j < 4; ++j) s[j] = (int)sls[beg + e + j];
      unsigned int v[4];
#pragma unroll
      for (int j = 0; j < 4; ++j)
        v[j] = *(const unsigned int*)(xb + (size_t)s[j] * 128 + 2 * lane);
      a0 += bflo(v[0]); a1 += bfhi(v[0]);
      b0 += bflo(v[1]); b1 += bfhi(v[1]);
      a0 += bflo(v[2]); a1 += bfhi(v[2]);
      b0 += bflo(v[3]); b1 += bfhi(v[3]);
    }
    for (; e < c; ++e) {
      const int s0 = (int)sls[beg + e];
      const unsigned int v0 = *(const unsigned int*)(xb + (size_t)s0 * 128 + 2 * lane);
      a0 += bflo(v0); a1 += bfhi(v0);
    }
    a0 += b0; a1 += b1;
    const float inv = (c > 0) ? __builtin_amdgcn_rcpf((float)c) : 0.f;
    Pu[tl][lane] = f2bf2(a0 * inv, a1 * inv);
  }
  __syncthreads();

  // Phase C: out[b*16 .. b*16+15][:] = P @ W via one MFMA m-tile per wave-col
  const int ncol = wave * 16 + l15;
  bf16x8 wb[4];
#pragma unroll
  for (int kc = 0; kc < 4; ++kc) {
    union { unsigned short h[8]; bf16x8 v; } u;
#pragma unroll
    for (int j = 0; j < 8; ++j)
      u.h[j] = f2bf(weight[(size_t)(kc * 32 + quad * 8 + j) * 128 + ncol]);
    wb[kc] = u.v;
  }
  f32x4 o0 = (f32x4){0.f, 0.f, 0.f, 0.f};
#pragma unroll
  for (int kc = 0; kc < 4; ++kc) {
    bf16x8 p0 = *(const bf16x8*)((const unsigned short*)&Pu[l15][0] + kc * 32 + quad * 8);
    o0 = __builtin_amdgcn_mfma_f32_16x16x32_bf16(p0, wb[kc], o0, 0, 0, 0);
  }
#pragma unroll
  for (int reg = 0; reg < 4; ++reg)
    out[((size_t)b * GT + quad * 4 + reg) * 128 + ncol] = o0[reg];
}

extern "C" void kernel_launch(void* const* d_in, const int* in_sizes, int n_in,
                              void* d_out, int out_size, void* d_ws, size_t ws_size,
                              hipStream_t stream) {
  const float* sf      = (const float*)d_in[0];   // [N,256] f32 (only rows < S used)
  const int*   src_idx = (const int*)d_in[1];     // [E]
  const int*   dst_idx = (const int*)d_in[2];     // [E]
  /* d_in[3] range_list: unused */
  const float* xn      = (const float*)d_in[4];   // [N]
  const float* embed   = (const float*)d_in[5];   // [256,128]
  const float* weight  = (const float*)d_in[6];   // [128,128]
  float* out = (float*)d_out;                     // [T,128] f32

  // workspace layout (16B-aligned), total ~32.0 MB
  char* w = (char*)d_ws;
  unsigned short* xb = (unsigned short*)(w);            // 25,600,000
  int* gcursor       = (int*)(w + 25600000);            // 8,192 (1250 used)
  unsigned int* ebuf = (unsigned int*)(w + 25608192);   // 1250*1280*4 = 6,400,000

  hipMemsetAsync(gcursor, 0, 8192, stream);
  k12_fused<<<KB2 + KB1, 512, 0, stream>>>(sf, xn, embed, xb, src_idx, dst_idx, gcursor, ebuf);
  k3_fused<<<NB, 512, 0, stream>>>(gcursor, ebuf, xb, weight, out);
}